// Round 9
// baseline (1954.195 us; speedup 1.0000x reference)
//
#include <hip/hip_runtime.h>
#include <stdint.h>

// SetAbstraction (PointNet++): B=4, N=8192, C=128, S=2048, K=32, R=0.1
// Numerics locked (R5 passed, absmax 0.0156):
//  - FPS: f32, d = ((dx*dx + dy*dy) + dz*dz) mul/add LTR (np.sum order)
//  - grouping: sq = (cc+pp) - 2*dot, dot = fma(cz,z, fma(cy,y, cx*x)) (BLAS)
//  - MLP: bf16 MFMA
// R9 kfps: per-iteration fixed cost scales with wave count (R8 evidence:
// LDS-pipe + skip-path issue ~16 waves). -> 512 thr / 8 waves x 16 pts,
// parity-buffered sKeys[2][8] block combine (no atomic), 3-stage DPP
// global max in all lanes, ksort 4x2 bins = 1 bin/wave bbox.

typedef unsigned short u16;
typedef unsigned long long u64;
typedef __bf16 bf16x8 __attribute__((ext_vector_type(8)));
typedef float f32x4 __attribute__((ext_vector_type(4)));
typedef float f32x2 __attribute__((ext_vector_type(2)));

#define NB 4
#define NPTS 8192
#define CH 128
#define SPTS 2048
#define KN 32
#define CINP 160   // 131 padded to 160 (5 k-steps of 32)

__device__ __forceinline__ u16 f2b(float f) {  // f32 -> bf16 RNE
    unsigned x = __float_as_uint(f);
    unsigned r = (x + 0x7fffu + ((x >> 16) & 1u)) >> 16;
    return (u16)r;
}
__device__ __forceinline__ u64 umin64(u64 a, u64 b) { return a < b ? a : b; }

template <int CTRL>
__device__ __forceinline__ u64 dpp_max64(u64 k) {
    unsigned lo = (unsigned)k, hi = (unsigned)(k >> 32);
    unsigned mlo = (unsigned)__builtin_amdgcn_update_dpp((int)lo, (int)lo, CTRL, 0xF, 0xF, false);
    unsigned mhi = (unsigned)__builtin_amdgcn_update_dpp((int)hi, (int)hi, CTRL, 0xF, 0xF, false);
    u64 m = ((u64)mhi << 32) | mlo;
    return m > k ? m : k;
}
// uint-bits max (== float max for non-negative floats)
template <int CTRL>
__device__ __forceinline__ unsigned dpp_maxu(unsigned v) {
    unsigned mv = (unsigned)__builtin_amdgcn_update_dpp((int)v, (int)v, CTRL, 0xF, 0xF, false);
    return mv > v ? mv : v;
}

// ---------------- transpose fea (B,C,N) f32 -> feaT (B,N,C) bf16 ----------------
__global__ __launch_bounds__(256) void ktrans(const float* __restrict__ fea,
                                              u16* __restrict__ feaT) {
    __shared__ u16 T[128][130];
    int blk = blockIdx.x;  // 4 b x 64 n-tiles
    int b = blk >> 6, nt = blk & 63;
    int n0 = nt * 128;
    int t = threadIdx.x;
#pragma unroll 4
    for (int it = 0; it < 64; ++it) {
        int idx = it * 256 + t;
        int c = idx >> 7, nl = idx & 127;
        T[nl][c] = f2b(fea[((size_t)(b * CH + c)) * NPTS + n0 + nl]);
    }
    __syncthreads();
#pragma unroll 4
    for (int it = 0; it < 64; ++it) {
        int idx = it * 256 + t;
        int nl = idx >> 7, c = idx & 127;
        feaT[((size_t)(b * NPTS + n0 + nl)) * CH + c] = T[nl][c];
    }
}

// ---------------- pp = |p|^2 (np.sum LTR), W pad to bf16 ----------------
__global__ __launch_bounds__(256) void kmisc(const float* __restrict__ coor,
                                             const float* __restrict__ W,
                                             float* __restrict__ pp,
                                             u16* __restrict__ Wpad) {
    int gid = blockIdx.x * 256 + threadIdx.x;
    if (blockIdx.x < 128) {
        int n = gid & 8191, b = gid >> 13;
        const float* cb = coor + b * 3 * NPTS;
        float x = cb[n], y = cb[NPTS + n], z = cb[2 * NPTS + n];
        pp[gid] = __fadd_rn(__fadd_rn(__fmul_rn(x, x), __fmul_rn(y, y)),
                            __fmul_rn(z, z));
    } else {
        int i = gid - 128 * 256;
        if (i < 256 * CINP) {
            int d = i / CINP, k = i - d * CINP;
            Wpad[i] = (k < 131) ? f2b(W[d * 131 + k]) : (u16)0;
        }
    }
}

// ---------------- spatial counting sort into 8 bins (4x2 xy) per batch ----------------
__global__ __launch_bounds__(256) void ksort(const float* __restrict__ coor,
                                             float* __restrict__ sxg,
                                             float* __restrict__ syg,
                                             float* __restrict__ szg,
                                             int* __restrict__ sog) {
    __shared__ int hist[8], base[8];
    int b = blockIdx.x, tid = threadIdx.x;
    const float* cb = coor + b * 3 * NPTS;
    if (tid < 8) hist[tid] = 0;
    __syncthreads();
    int bins[32];
#pragma unroll 4
    for (int i = 0; i < 32; ++i) {
        int n = tid * 32 + i;
        float x = cb[n], y = cb[NPTS + n];
        int bx = min(3, (int)(x * 4.0f));
        int by = min(1, (int)(y * 2.0f));
        int bin = by * 4 + bx;
        bins[i] = bin;
        atomicAdd(&hist[bin], 1);
    }
    __syncthreads();
    if (tid == 0) {
        int acc = 0;
        for (int k2 = 0; k2 < 8; ++k2) { base[k2] = acc; acc += hist[k2]; hist[k2] = 0; }
    }
    __syncthreads();
#pragma unroll 4
    for (int i = 0; i < 32; ++i) {
        int n = tid * 32 + i;
        int bin = bins[i];
        int pos = base[bin] + atomicAdd(&hist[bin], 1);
        sxg[b * NPTS + pos] = cb[n];
        syg[b * NPTS + pos] = cb[NPTS + n];
        szg[b * NPTS + pos] = cb[2 * NPTS + n];
        sog[b * NPTS + pos] = n;
    }
}

// ---------------- FPS v5: 1 block (512 thr, 8 waves) per batch ----------------
__global__ __launch_bounds__(512) void kfps(const float* __restrict__ sxg,
                                            const float* __restrict__ syg,
                                            const float* __restrict__ szg,
                                            const int* __restrict__ sog,
                                            int* __restrict__ fpsIdx,
                                            float* __restrict__ outCoor) {
    __shared__ float4 sp[NPTS];          // 128 KB
    __shared__ unsigned sWin[SPTS];      // 8 KB
    __shared__ u64 sKeys[2][8];          // parity double-buffer
    __shared__ int slot0s;
    int tid = threadIdx.x;
    int b = blockIdx.x;
    int w = tid >> 6, lane = tid & 63;
    const float* gx = sxg + b * NPTS;
    const float* gy = syg + b * NPTS;
    const float* gz = szg + b * NPTS;
    const int* go = sog + b * NPTS;
    f32x2 X2[8], Y2[8], Z2[8], D2[8];
    unsigned PK[16];
    int n0 = tid * 16;
#pragma unroll
    for (int j = 0; j < 16; ++j) {
        float x = gx[n0 + j], y = gy[n0 + j], z = gz[n0 + j];
        sp[n0 + j] = make_float4(x, y, z, 0.0f);
        X2[j >> 1][j & 1] = x; Y2[j >> 1][j & 1] = y; Z2[j >> 1][j & 1] = z;
        D2[j >> 1][j & 1] = 1e10f;
        int oi = go[n0 + j];
        PK[j] = ((unsigned)oi << 16) | (unsigned)(n0 + j);
        if (oi == 0) slot0s = n0 + j;
    }
    // wave bbox (used conservatively; exactness irrelevant)
    float lox = X2[0][0], hix = lox, loy = Y2[0][0], hiy = loy, loz = Z2[0][0], hiz = loz;
#pragma unroll
    for (int j = 1; j < 16; ++j) {
        float x = X2[j >> 1][j & 1], y = Y2[j >> 1][j & 1], z = Z2[j >> 1][j & 1];
        lox = fminf(lox, x); hix = fmaxf(hix, x);
        loy = fminf(loy, y); hiy = fmaxf(hiy, y);
        loz = fminf(loz, z); hiz = fmaxf(hiz, z);
    }
#pragma unroll
    for (int off = 32; off > 0; off >>= 1) {
        lox = fminf(lox, __shfl_xor(lox, off)); hix = fmaxf(hix, __shfl_xor(hix, off));
        loy = fminf(loy, __shfl_xor(loy, off)); hiy = fmaxf(hiy, __shfl_xor(hiy, off));
        loz = fminf(loz, __shfl_xor(loz, off)); hiz = fmaxf(hiz, __shfl_xor(hiz, off));
    }
    __syncthreads();
    int far = slot0s;
    if (tid == 0) sWin[0] = (unsigned)slot0s;  // origIdx 0 in high bits
    float wMaxF = 3.4e38f;  // force update on first iteration
    u64 cachedKey = 1;      // any real key beats it
    for (int t = 1; t < SPTS; ++t) {
        float4 c = sp[far];  // uniform addr -> broadcast ds_read_b128
        float fx = c.x, fy = c.y, fz = c.z;
        // exact-no-op skip: min dist(c, wave bbox)^2 vs max D at last update
        float ddx = fmaxf(0.0f, fmaxf(lox - fx, fx - hix));
        float ddy = fmaxf(0.0f, fmaxf(loy - fy, fy - hiy));
        float ddz = fmaxf(0.0f, fmaxf(loz - fz, fz - hiz));
        float dmin2 = ddx * ddx + ddy * ddy + ddz * ddz;
        if (!(dmin2 * 0.9995f >= wMaxF)) {  // wave-uniform branch
            {
#pragma clang fp contract(off)
                f32x2 fx2 = {fx, fx}, fy2 = {fy, fy}, fz2 = {fz, fz};
#pragma unroll
                for (int i = 0; i < 8; ++i) {
                    f32x2 dx = X2[i] - fx2;
                    f32x2 dy = Y2[i] - fy2;
                    f32x2 dz = Z2[i] - fz2;
                    f32x2 s = (dx * dx + dy * dy) + dz * dz;  // per-elem RN, np order
                    D2[i][0] = fminf(D2[i][0], s[0]);
                    D2[i][1] = fminf(D2[i][1], s[1]);
                }
            }
            // thread argmax over 16: value tree, then min-PK among ties
            float mt_[8];
#pragma unroll
            for (int i = 0; i < 8; ++i) mt_[i] = fmaxf(D2[i][0], D2[i][1]);
            float m0 = fmaxf(fmaxf(mt_[0], mt_[1]), fmaxf(mt_[2], mt_[3]));
            float m1 = fmaxf(fmaxf(mt_[4], mt_[5]), fmaxf(mt_[6], mt_[7]));
            float m = fmaxf(m0, m1);
            unsigned sel = 0xFFFFFFFFu;
#pragma unroll
            for (int j = 0; j < 16; ++j) {
                float dj = D2[j >> 1][j & 1];
                sel = (dj == m) ? (sel < PK[j] ? sel : PK[j]) : sel;
            }
            // wave value-max via DPP on float bits (all >= 0)
            unsigned mbits = __float_as_uint(m);
            unsigned r = mbits;
            r = dpp_maxu<0xB1>(r);    // quad_perm xor1
            r = dpp_maxu<0x4E>(r);    // quad_perm xor2
            r = dpp_maxu<0x141>(r);   // row_half_mirror
            r = dpp_maxu<0x140>(r);   // row_mirror
            r = dpp_maxu<0x142>(r);   // row_bcast:15
            r = dpp_maxu<0x143>(r);   // row_bcast:31
            unsigned wmaxb = (unsigned)__builtin_amdgcn_readlane((int)r, 63);
            u64 ball = __ballot(mbits == wmaxb);
            unsigned wpk;
            if (__popcll(ball) == 1) {  // unique winner lane (common)
                int l = __ffsll(ball) - 1;
                wpk = (unsigned)__builtin_amdgcn_readlane((int)sel, l);
            } else {                    // rare: cross-lane value tie
                u64 kk = (mbits == wmaxb) ? (((u64)wmaxb << 32) | (unsigned)~sel) : 0ull;
                kk = dpp_max64<0xB1>(kk);
                kk = dpp_max64<0x4E>(kk);
                kk = dpp_max64<0x141>(kk);
                kk = dpp_max64<0x140>(kk);
                kk = dpp_max64<0x142>(kk);
                kk = dpp_max64<0x143>(kk);
                unsigned lo = (unsigned)__builtin_amdgcn_readlane((int)(unsigned)kk, 63);
                wpk = ~lo;
            }
            cachedKey = ((u64)wmaxb << 32) | (unsigned)~wpk;
            wMaxF = __uint_as_float(wmaxb);
        }
        int p = t & 1;
        if (lane == 63) sKeys[p][w] = cachedKey;
        __syncthreads();
        // all lanes gather the 8 wave keys and reduce in 3 DPP stages
        u64 kk = sKeys[p][lane & 7];
        kk = dpp_max64<0xB1>(kk);    // xor1
        kk = dpp_max64<0x4E>(kk);    // xor2
        kk = dpp_max64<0x141>(kk);   // half mirror: max over 8
        unsigned pk = ~(unsigned)kk;
        far = (int)(pk & 0xFFFFu);
        if (tid == 0) sWin[t] = pk;
    }
    __syncthreads();
    // deferred flush
    for (int i = tid; i < SPTS; i += 512) {
        unsigned pk = sWin[i];
        int slot = (int)(pk & 0xFFFFu);
        float4 c = sp[slot];
        fpsIdx[b * SPTS + i] = (int)(pk >> 16);
        float* oc = outCoor + b * 3 * SPTS + i;
        oc[0] = c.x; oc[SPTS] = c.y; oc[2 * SPTS] = c.z;
    }
}

// ---------------- grouping (exact f32, GEMM-style FMA dot): 1 wave/row ----------------
__global__ __launch_bounds__(256) void kgroup(const float* __restrict__ coor,
                                              const float* __restrict__ pp,
                                              const int* __restrict__ fpsIdx,
                                              int* __restrict__ gidxOut) {
    __shared__ u64 buf[4][256];
    __shared__ int cnt[4];
    int tid = threadIdx.x;
    int wv = tid >> 6, lane = tid & 63;
    if (tid < 4) cnt[tid] = 0;
    __syncthreads();
    int row = blockIdx.x * 4 + wv;
    int b = row >> 11, s = row & 2047;
    const float* cb = coor + b * 3 * NPTS;
    int n0 = fpsIdx[b * SPTS + s];
    float cx = cb[n0], cy = cb[NPTS + n0], cz = cb[2 * NPTS + n0];
    float cc = __fadd_rn(__fadd_rn(__fmul_rn(cx, cx), __fmul_rn(cy, cy)),
                         __fmul_rn(cz, cz));
    const float* ppb = pp + b * NPTS;
    u64 mk = ~0ull;
    for (int n = lane; n < NPTS; n += 64) {
        float x = cb[n], y = cb[NPTS + n], z = cb[2 * NPTS + n];
        float dot = __fmaf_rn(cz, z, __fmaf_rn(cy, y, __fmul_rn(cx, x)));
        float sq = __fsub_rn(__fadd_rn(cc, ppb[n]), __fmul_rn(2.0f, dot));
        unsigned ub = __float_as_uint(sq);
        ub ^= (ub >> 31) ? 0xFFFFFFFFu : 0x80000000u;
        u64 key = ((u64)ub << 32) | (unsigned)n;
        mk = umin64(mk, key);
        if (sq <= 0.01f) {
            int p = atomicAdd(&cnt[wv], 1);
            if (p < 256) buf[wv][p] = key;
        }
    }
#pragma unroll
    for (int off = 32; off > 0; off >>= 1) mk = umin64(mk, __shfl_xor(mk, off));
    int C = cnt[wv];
    if (C > 256) C = 256;
    int* go = gidxOut + row * KN;
    if (C <= 32) {
        if (lane < 32) {
            unsigned idx = (lane < C) ? (unsigned)buf[wv][lane] : (unsigned)mk;
            go[lane] = (int)idx;
        }
    } else {
        u64 e[4];
#pragma unroll
        for (int i = 0; i < 4; ++i) {
            int j2 = lane + (i << 6);
            e[i] = (j2 < C) ? buf[wv][j2] : ~0ull;
        }
        int cl = 0;
        unsigned sel = 0;
        for (int it = 0; it < 32; ++it) {
            u64 lb = ~0ull;
            int li = 0;
#pragma unroll
            for (int i = 0; i < 4; ++i) {
                bool f = (((cl >> i) & 1) == 0) && (e[i] < lb);
                lb = f ? e[i] : lb;
                li = f ? i : li;
            }
            u64 wmin = lb;
#pragma unroll
            for (int off = 32; off > 0; off >>= 1) wmin = umin64(wmin, __shfl_xor(wmin, off));
            u64 bal = __ballot(lb == wmin);
            int src = __ffsll((unsigned long long)bal) - 1;
            if (lane == src) cl |= (1 << li);
            if (lane == it) sel = (unsigned)wmin;
        }
        if (lane < 32) go[lane] = (int)sel;
    }
}

// ---------------- MLP + BN + ReLU + maxpool: 1 block per (b,s) row ----------------
__global__ __launch_bounds__(256) void kfeat(const float* __restrict__ coor,
                                             const u16* __restrict__ feaT,
                                             const u16* __restrict__ Wpad,
                                             const float* __restrict__ bias,
                                             const float* __restrict__ gamma,
                                             const float* __restrict__ beta,
                                             const float* __restrict__ bmean,
                                             const float* __restrict__ bvar,
                                             const int* __restrict__ fpsIdx,
                                             const int* __restrict__ gidx,
                                             float* __restrict__ outFea) {
    __shared__ u16 g[KN][168];
    int row = blockIdx.x;
    int b = row >> 11, s = row & 2047;
    int tid = threadIdx.x;
    {
        int k = tid >> 3, j = tid & 7;
        const float* cb = coor + b * 3 * NPTS;
        int nc = fpsIdx[b * SPTS + s];
        int nbr = gidx[row * KN + k];
        const uint4* f4 = (const uint4*)(feaT + (((size_t)b * NPTS + nbr) << 7));
        uint4* gr = (uint4*)&g[k][0];
        gr[j] = f4[j];
        gr[j + 8] = f4[j + 8];
        for (int c = 128 + j; c < CINP; c += 8) {
            u16 v = 0;
            if (c < 131) {
                int dim = c - 128;
                float pv = cb[dim * NPTS + nbr];
                float cv = cb[dim * NPTS + nc];
                v = f2b(__fdiv_rn(__fsub_rn(pv, cv), 0.1f));
            }
            g[k][c] = v;
        }
    }
    __syncthreads();
    int w = tid >> 6, lane = tid & 63;
    int mrow = lane & 15, q = lane >> 4;
    f32x4 acc[4][2] = {};
#pragma unroll
    for (int ks = 0; ks < 5; ++ks) {
        int kb = ks * 32 + q * 8;
        bf16x8 b0 = *(const bf16x8*)&g[mrow][kb];
        bf16x8 b1 = *(const bf16x8*)&g[mrow + 16][kb];
#pragma unroll
        for (int mt = 0; mt < 4; ++mt) {
            bf16x8 a = *(const bf16x8*)&Wpad[(size_t)(w * 64 + mt * 16 + mrow) * CINP + kb];
            acc[mt][0] = __builtin_amdgcn_mfma_f32_16x16x32_bf16(a, b0, acc[mt][0], 0, 0, 0);
            acc[mt][1] = __builtin_amdgcn_mfma_f32_16x16x32_bf16(a, b1, acc[mt][1], 0, 0, 0);
        }
    }
#pragma unroll
    for (int mt = 0; mt < 4; ++mt) {
#pragma unroll
        for (int r = 0; r < 4; ++r) {
            int m = w * 64 + mt * 16 + q * 4 + r;
            float ga = gamma[m], be = beta[m];
            float mu = bmean[m], va = bvar[m], bi = bias[m];
            float rs = 1.0f / sqrtf(va + 1e-5f);
            float h0 = acc[mt][0][r] + bi;
            h0 = fmaxf(ga * (h0 - mu) * rs + be, 0.0f);
            float h1 = acc[mt][1][r] + bi;
            h1 = fmaxf(ga * (h1 - mu) * rs + be, 0.0f);
            float v = fmaxf(h0, h1);
#pragma unroll
            for (int off = 1; off < 16; off <<= 1) v = fmaxf(v, __shfl_xor(v, off));
            if (mrow == 0) outFea[((size_t)(b * 256 + m)) * SPTS + s] = v;
        }
    }
}

extern "C" void kernel_launch(void* const* d_in, const int* in_sizes, int n_in,
                              void* d_out, int out_size, void* d_ws, size_t ws_size,
                              hipStream_t stream) {
    const float* coor = (const float*)d_in[0];
    const float* fea = (const float*)d_in[1];
    const float* W = (const float*)d_in[2];
    const float* bias = (const float*)d_in[3];
    const float* gamma = (const float*)d_in[4];
    const float* beta = (const float*)d_in[5];
    const float* bmean = (const float*)d_in[6];
    const float* bvar = (const float*)d_in[7];
    char* ws = (char*)d_ws;
    int* fpsIdx = (int*)ws;                              // 32 KB
    int* gidx = (int*)(ws + 32768);                      // 1 MB
    float* pp = (float*)(ws + 32768 + 1048576);          // 128 KB
    u16* feaT = (u16*)(ws + 1212416);                    // 8 MB bf16
    u16* Wpad = (u16*)(ws + 9601024);                    // 80 KB bf16
    float* sxg = (float*)(ws + 9682944);                 // 128 KB
    float* syg = (float*)(ws + 9814016);                 // 128 KB
    float* szg = (float*)(ws + 9945088);                 // 128 KB
    int* sog = (int*)(ws + 10076160);                    // 128 KB
    float* outC = (float*)d_out;                         // (B,3,S) f32
    float* outF = outC + NB * 3 * SPTS;                  // (B,2C,S) f32

    ktrans<<<256, 256, 0, stream>>>(fea, feaT);
    kmisc<<<288, 256, 0, stream>>>(coor, W, pp, Wpad);
    ksort<<<NB, 256, 0, stream>>>(coor, sxg, syg, szg, sog);
    kfps<<<NB, 512, 0, stream>>>(sxg, syg, szg, sog, fpsIdx, outC);
    kgroup<<<2048, 256, 0, stream>>>(coor, pp, fpsIdx, gidx);
    kfeat<<<8192, 256, 0, stream>>>(coor, feaT, Wpad, bias, gamma, beta, bmean, bvar,
                                    fpsIdx, gidx, outF);
}